// Round 2
// baseline (312.668 us; speedup 1.0000x reference)
//
#include <hip/hip_runtime.h>
#include <math.h>

#define NN 65536
#define NE 1048576
#define KH 48
#define G3 144

#define CAP_L1 8192
#define CAP_S1 4096
#define CAP_E2 65536
#define CAP_S2 8192

// ws byte offsets (all 256-aligned), total ~4.05 MB
#define OFF_DEG    0u        // NN f32
#define OFF_MARK1  262144u   // NN i32
#define OFF_MARK2  524288u   // NN i32
#define OFF_CNT    786432u   // 16 u32: [0]=cntL1 [1]=cnt1 [2]=cntE2 [3]=cnt2
#define OFF_L1R    803072u   // CAP_L1 i32
#define OFF_L1W    835840u   // CAP_L1 f32
#define OFF_E2R    868608u   // CAP_E2 i32
#define OFF_E2S    1130752u  // CAP_E2 i32
#define OFF_E2N    1392896u  // CAP_E2 f32
#define OFF_S2     1655040u  // CAP_S2 i32
#define OFF_STATE  1687808u  // CAP_S2*48 f32
#define OFF_X1     3260672u  // CAP_S1*48 f32
#define OFF_TPSF   4047104u  // 128 f32: [0..47]=target_past, [64..111]=state_fut

__device__ __forceinline__ float sigmf(float x) { return 1.0f / (1.0f + expf(-x)); }

// ---------------- K0: init ----------------
__global__ void k_init(float* deg, int* mark1, int* mark2, unsigned* cnt) {
    int i = blockIdx.x * blockDim.x + threadIdx.x;
    if (i < NN) {
        deg[i] = 1.0f;               // self-loop weight
        mark1[i] = (i == 0) ? 1 : 0; // node 0 always needed
        mark2[i] = 0;
    }
    if (i < 16) cnt[i] = 0;
}

// ---------------- K1: deg + edges into node 0 (4 edges/thread) ----------------
__global__ void k_edges1(const int* ei, const float* ew, float* deg,
                         int* mark1, unsigned* cnt, int* l1r, float* l1w) {
    int q = blockIdx.x * blockDim.x + threadIdx.x;
    if (q >= NE / 4) return;
    int4 c4 = reinterpret_cast<const int4*>(ei + NE)[q];
    float4 w4 = reinterpret_cast<const float4*>(ew)[q];
    atomicAdd(&deg[c4.x], w4.x);
    atomicAdd(&deg[c4.y], w4.y);
    atomicAdd(&deg[c4.z], w4.z);
    atomicAdd(&deg[c4.w], w4.w);
    int e = q * 4;
    int cc[4] = {c4.x, c4.y, c4.z, c4.w};
    float wc[4] = {w4.x, w4.y, w4.z, w4.w};
#pragma unroll
    for (int j = 0; j < 4; ++j) {
        if (cc[j] == 0) {
            int r = ei[e + j];
            unsigned s = atomicAdd(&cnt[0], 1u);
            if (s < CAP_L1) { l1r[s] = r; l1w[s] = wc[j]; }
            mark1[r] = 1;
        }
    }
}

// ---------------- K2: compact S1, emit self-loop E2 entries, init x1 rows --
__global__ void k_compact1(int* mark1, int* mark2, unsigned* cnt,
                           int* e2r, int* e2s, float* e2n, const float* deg,
                           float* x1, const float* g1b) {
    int i = blockIdx.x * blockDim.x + threadIdx.x;
    if (i >= NN) return;
    if (mark1[i]) {
        unsigned s = atomicAdd(&cnt[1], 1u);
        if (s < CAP_S1) {
            mark1[i] = (int)s + 1;
            mark2[i] = 1;                      // need own GRU state (self loop)
            unsigned t = atomicAdd(&cnt[2], 1u);
            if (t < CAP_E2) { e2r[t] = i; e2s[t] = (int)s; e2n[t] = 1.0f / deg[i]; }
            for (int k = 0; k < KH; ++k) x1[s * KH + k] = g1b[k];
        } else {
            mark1[i] = 0;
        }
    }
}

// ---------------- K3: collect edges into S1 (4 edges/thread) ----------------
__global__ void k_edges2(const int* ei, const float* ew, const float* deg,
                         const int* mark1, int* mark2, unsigned* cnt,
                         int* e2r, int* e2s, float* e2n) {
    int q = blockIdx.x * blockDim.x + threadIdx.x;
    if (q >= NE / 4) return;
    int4 c4 = reinterpret_cast<const int4*>(ei + NE)[q];
    int e = q * 4;
    int cc[4] = {c4.x, c4.y, c4.z, c4.w};
#pragma unroll
    for (int j = 0; j < 4; ++j) {
        int m = mark1[cc[j]];
        if (m > 0) {
            int r = ei[e + j];
            float w = ew[e + j];
            unsigned s = atomicAdd(&cnt[2], 1u);
            if (s < CAP_E2) {
                e2r[s] = r; e2s[s] = m - 1;
                e2n[s] = w * rsqrtf(deg[r] * deg[cc[j]]);
            }
            mark2[r] = 1;
        }
    }
}

// ---------------- K4: compact S2 ----------------
__global__ void k_compact2(int* mark2, unsigned* cnt, int* s2) {
    int i = blockIdx.x * blockDim.x + threadIdx.x;
    if (i >= NN) return;
    if (mark2[i]) {
        unsigned s = atomicAdd(&cnt[3], 1u);
        if (s < CAP_S2) { s2[s] = i; mark2[i] = (int)s + 1; }
        else mark2[i] = 0;
    }
}

// ---------------- conv1d(pad=1,k=3) + GRU over one sequence ----------------
// gi = Wih@embed + bih precomputed for ALL steps in parallel (not recurrent);
// recurrence holds only 12 float4 of Whh per thread -> no spill.
__device__ void gru_seq(const float* xseq, int T,
                        const float* cw, const float* cb,
                        const float* Wih, const float* Whh,
                        const float* bih, const float* bhh,
                        float* out48,
                        float* s_x, float* s_embed, float* s_giA,
                        float* s_h, float* s_gh) {
    int t = threadIdx.x;
    int nt = blockDim.x;
    for (int i = t; i < T * 2; i += nt) s_x[i] = xseq[i];
    __syncthreads();
    // conv + relu -> embed[t][k]
    for (int idx = t; idx < T * KH; idx += nt) {
        int tt = idx / KH;
        int k = idx - tt * KH;
        float acc = cb[k];
#pragma unroll
        for (int d = 0; d < 3; ++d) {
            int tau = tt + d - 1;
            if (tau >= 0 && tau < T) {
                acc += cw[k * 6 + d] * s_x[tau * 2 + 0];
                acc += cw[k * 6 + 3 + d] * s_x[tau * 2 + 1];
            }
        }
        s_embed[tt * KH + k] = fmaxf(acc, 0.0f);
    }
    __syncthreads();
    // precompute gi for all steps (parallel over T*G3 items)
    for (int idx = t; idx < T * G3; idx += nt) {
        int step = idx / G3;
        int row = idx - step * G3;
        const float4* wp = reinterpret_cast<const float4*>(Wih + row * KH);
        const float4* em = reinterpret_cast<const float4*>(s_embed + step * KH);
        float g = bih[row];
#pragma unroll
        for (int j = 0; j < 12; ++j) {
            float4 w4 = wp[j]; float4 e4 = em[j];
            g += w4.x * e4.x + w4.y * e4.y + w4.z * e4.z + w4.w * e4.w;
        }
        s_giA[idx] = g;
    }
    // Whh rows in registers (48 VGPRs)
    float4 wh[12];
    float bh = 0.0f;
    if (t < G3) {
        const float4* q = reinterpret_cast<const float4*>(Whh + t * KH);
#pragma unroll
        for (int j = 0; j < 12; ++j) wh[j] = q[j];
        bh = bhh[t];
    }
    if (t < KH) s_h[t] = 0.0f;
    __syncthreads();
    for (int step = 0; step < T; ++step) {
        if (t < G3) {
            const float4* hp = reinterpret_cast<const float4*>(s_h);
            float g = bh;
#pragma unroll
            for (int j = 0; j < 12; ++j) {
                float4 h4 = hp[j];
                g += wh[j].x * h4.x + wh[j].y * h4.y + wh[j].z * h4.z + wh[j].w * h4.w;
            }
            s_gh[t] = g;
        }
        __syncthreads();
        if (t < KH) {
            const float* gi = s_giA + step * G3;
            float r = sigmf(gi[t] + s_gh[t]);
            float z = sigmf(gi[KH + t] + s_gh[KH + t]);
            float n = tanhf(gi[2 * KH + t] + r * s_gh[2 * KH + t]);
            s_h[t] = (1.0f - z) * n + z * s_h[t];
        }
        __syncthreads();
    }
    if (t < KH) out48[t] = s_h[t];
}

// ---------------- K5: all GRUs (S2 nodes + target_past + state_fut) -------
__global__ __launch_bounds__(192) void k_gru(
    const float* x, const float* cpw, const float* cpb,
    const float* epWih, const float* epWhh, const float* epbih, const float* epbhh,
    const float* cfw, const float* cfb,
    const float* efWih, const float* efWhh, const float* efbih, const float* efbhh,
    const float* past, const float* future,
    const int* s2, const unsigned* cnt, float* state, float* tpsf) {
    __shared__ __align__(16) float s_x[80];
    __shared__ __align__(16) float s_embed[40 * KH];
    __shared__ __align__(16) float s_giA[40 * G3];
    __shared__ __align__(16) float s_h[KH];
    __shared__ float s_gh[G3];
    int nb = gridDim.x;
    if (blockIdx.x == nb - 1) {
        gru_seq(past, 20, cpw, cpb, epWih, epWhh, epbih, epbhh,
                tpsf, s_x, s_embed, s_giA, s_h, s_gh);
        return;
    }
    if (blockIdx.x == nb - 2) {
        gru_seq(future, 40, cfw, cfb, efWih, efWhh, efbih, efbhh,
                tpsf + 64, s_x, s_embed, s_giA, s_h, s_gh);
        return;
    }
    int cnt2 = (int)min(cnt[3], (unsigned)CAP_S2);
    for (int b = blockIdx.x; b < cnt2; b += nb - 2) {
        int node = s2[b];
        gru_seq(x + (size_t)node * 40, 20, cpw, cpb, epWih, epWhh, epbih, epbhh,
                state + (size_t)b * KH, s_x, s_embed, s_giA, s_h, s_gh);
    }
}

// ---------------- K6: GCN layer 1 edge accumulation ----------------
__global__ void k_acc1(const unsigned* cnt, const int* e2r, const int* e2s,
                       const float* e2n, const int* mark2, const float* state,
                       const float* W1, float* x1) {
    int nE = (int)min(cnt[2], (unsigned)CAP_E2);
    int total = nE * KH;
    int stride = gridDim.x * blockDim.x;
    for (int idx = blockIdx.x * blockDim.x + threadIdx.x; idx < total; idx += stride) {
        int e = idx / KH;
        int k = idx - e * KH;
        int row = e2r[e];
        int s2i = mark2[row] - 1;
        if (s2i < 0) continue;
        const float* sp = state + (size_t)s2i * KH;
        const float* wp = W1 + k * KH;
        float acc = 0.0f;
#pragma unroll
        for (int m = 0; m < KH; ++m) acc += sp[m] * wp[m];
        atomicAdd(&x1[e2s[e] * KH + k], acc * e2n[e]);
    }
}

// ---------------- K7: GCN layer 2 @ node 0 + decoder ----------------
// dWhh rows split across thread pairs: 864 active threads, 18 float4 (72 VGPR)
// each, halves combined with __shfl_xor(g,1) -> no register spill.
__global__ __launch_bounds__(896) void k_dec(
    const unsigned* cnt, const int* l1r, const float* l1w,
    const int* mark1, const float* deg, const float* x1,
    const float* W2, const float* b2, const float* tpsf, const float* past,
    const float* dWih, const float* dWhh, const float* dbih, const float* dbhh,
    const float* fcw, const float* fcb, float* out) {
    __shared__ __align__(16) float s_conc[G3];
    __shared__ __align__(16) float s_h[G3];
    __shared__ float s_gi0[3 * G3], s_gh[3 * G3], s_bih[3 * G3];
    int t = threadIdx.x;
    // state_conc = [interact_past, target_past, state_fut]
    if (t < 48) s_conc[t] = b2[t];
    else if (t < 96) s_conc[t] = tpsf[t - 48];
    else if (t < 144) s_conc[t] = tpsf[64 + t - 96];
    if (t < 3 * G3) s_bih[t] = dbih[t];
    __syncthreads();
    // layer-2 message accumulation into s_conc[0..47]
    int cl1 = (int)min(cnt[0], (unsigned)CAP_L1);
    float dinv0 = rsqrtf(deg[0]);
    int items = (cl1 + 1) * KH;
    for (int idx = t; idx < items; idx += blockDim.x) {
        int e = idx / KH;
        int k = idx - e * KH;
        int row; float norm;
        if (e == cl1) { row = 0; norm = dinv0 * dinv0; }
        else { row = l1r[e]; norm = l1w[e] * rsqrtf(deg[row]) * dinv0; }
        int s1 = mark1[row] - 1;
        if (s1 < 0) continue;
        const float* xp = x1 + (size_t)s1 * KH;
        const float* wp = W2 + k * KH;
        float acc = 0.0f;
#pragma unroll
        for (int m = 0; m < KH; ++m) acc += fmaxf(xp[m], 0.0f) * wp[m];
        atomicAdd(&s_conc[k], acc * norm);
    }
    // decoder setup: half-row of dWhh per thread
    int row = t >> 1, half = t & 1;
    float4 wh[18];
    float bh2 = 0.0f;
    if (t < 864) {
        const float4* q = reinterpret_cast<const float4*>(dWhh + row * G3 + half * 72);
#pragma unroll
        for (int j = 0; j < 18; ++j) wh[j] = q[j];
        if (half == 0) bh2 = dbhh[row];
    }
    if (t < G3) s_h[t] = 0.0f;
    float pres = 0.0f;
    if (t == 0 || t == 64) pres = past[38 + (t >> 6)];
    __syncthreads();   // s_conc complete
    // gi at step 0: dWih @ conc + dbih  (steps >=1: input is zeros -> gi = dbih)
    if (t < 864) {
        const float4* p = reinterpret_cast<const float4*>(dWih + row * G3 + half * 72);
        const float4* cc = reinterpret_cast<const float4*>(s_conc + half * 72);
        float g = 0.0f;
#pragma unroll
        for (int j = 0; j < 18; ++j) {
            float4 w4 = p[j]; float4 c4 = cc[j];
            g += w4.x * c4.x + w4.y * c4.y + w4.z * c4.z + w4.w * c4.w;
        }
        g += __shfl_xor(g, 1);
        if (half == 0) s_gi0[row] = g + s_bih[row];
    }
    for (int i = 0; i < 40; ++i) {
        if (t < 864) {
            const float4* hp = reinterpret_cast<const float4*>(s_h + half * 72);
            float g = 0.0f;
#pragma unroll
            for (int j = 0; j < 18; ++j) {
                float4 h4 = hp[j];
                g += wh[j].x * h4.x + wh[j].y * h4.y + wh[j].z * h4.z + wh[j].w * h4.w;
            }
            g += __shfl_xor(g, 1);
            if (half == 0) s_gh[row] = g + bh2;
        }
        __syncthreads();
        if (t < G3) {
            float gr = (i == 0) ? s_gi0[t] : s_bih[t];
            float gz = (i == 0) ? s_gi0[G3 + t] : s_bih[G3 + t];
            float gn = (i == 0) ? s_gi0[2 * G3 + t] : s_bih[2 * G3 + t];
            float r = sigmf(gr + s_gh[t]);
            float z = sigmf(gz + s_gh[G3 + t]);
            float n = tanhf(gn + r * s_gh[2 * G3 + t]);
            s_h[t] = (1.0f - z) * n + z * s_h[t];
        }
        __syncthreads();
        // coords = present + h @ fc_w.T + fc_b ; two wave-reductions
        int w = t >> 6;
        if (w < 2) {
            int lane = t & 63;
            float p = 0.0f;
            for (int m = lane; m < G3; m += 64) p += s_h[m] * fcw[w * G3 + m];
#pragma unroll
            for (int off = 32; off > 0; off >>= 1) p += __shfl_down(p, off);
            if (lane == 0) {
                pres += p + fcb[w];
                out[i * 2 + w] = pres;
            }
        }
    }
}

extern "C" void kernel_launch(void* const* d_in, const int* in_sizes, int n_in,
                              void* d_out, int out_size, void* d_ws, size_t ws_size,
                              hipStream_t stream) {
    (void)in_sizes; (void)n_in; (void)out_size; (void)ws_size;
    const float* past   = (const float*)d_in[0];
    const float* future = (const float*)d_in[1];
    const float* x      = (const float*)d_in[2];
    const int*   ei     = (const int*)d_in[3];
    const float* ew     = (const float*)d_in[4];
    const float* cpw    = (const float*)d_in[5];
    const float* cpb    = (const float*)d_in[6];
    const float* cfw    = (const float*)d_in[7];
    const float* cfb    = (const float*)d_in[8];
    const float* epWih  = (const float*)d_in[9];
    const float* epWhh  = (const float*)d_in[10];
    const float* epbih  = (const float*)d_in[11];
    const float* epbhh  = (const float*)d_in[12];
    const float* efWih  = (const float*)d_in[13];
    const float* efWhh  = (const float*)d_in[14];
    const float* efbih  = (const float*)d_in[15];
    const float* efbhh  = (const float*)d_in[16];
    const float* dWih   = (const float*)d_in[17];
    const float* dWhh   = (const float*)d_in[18];
    const float* dbih   = (const float*)d_in[19];
    const float* dbhh   = (const float*)d_in[20];
    const float* fcw    = (const float*)d_in[21];
    const float* fcb    = (const float*)d_in[22];
    const float* g1w    = (const float*)d_in[23];
    const float* g1b    = (const float*)d_in[24];
    const float* g2w    = (const float*)d_in[25];
    const float* g2b    = (const float*)d_in[26];

    char* ws = (char*)d_ws;
    float*    deg   = (float*)(ws + OFF_DEG);
    int*      mark1 = (int*)(ws + OFF_MARK1);
    int*      mark2 = (int*)(ws + OFF_MARK2);
    unsigned* cnt   = (unsigned*)(ws + OFF_CNT);
    int*      l1r   = (int*)(ws + OFF_L1R);
    float*    l1w   = (float*)(ws + OFF_L1W);
    int*      e2r   = (int*)(ws + OFF_E2R);
    int*      e2s   = (int*)(ws + OFF_E2S);
    float*    e2n   = (float*)(ws + OFF_E2N);
    int*      s2    = (int*)(ws + OFF_S2);
    float*    state = (float*)(ws + OFF_STATE);
    float*    x1    = (float*)(ws + OFF_X1);
    float*    tpsf  = (float*)(ws + OFF_TPSF);

    k_init<<<NN / 256, 256, 0, stream>>>(deg, mark1, mark2, cnt);
    k_edges1<<<NE / 4 / 256, 256, 0, stream>>>(ei, ew, deg, mark1, cnt, l1r, l1w);
    k_compact1<<<NN / 256, 256, 0, stream>>>(mark1, mark2, cnt, e2r, e2s, e2n, deg, x1, g1b);
    k_edges2<<<NE / 4 / 256, 256, 0, stream>>>(ei, ew, deg, mark1, mark2, cnt, e2r, e2s, e2n);
    k_compact2<<<NN / 256, 256, 0, stream>>>(mark2, cnt, s2);
    k_gru<<<514, 192, 0, stream>>>(x, cpw, cpb, epWih, epWhh, epbih, epbhh,
                                   cfw, cfb, efWih, efWhh, efbih, efbhh,
                                   past, future, s2, cnt, state, tpsf);
    k_acc1<<<128, 256, 0, stream>>>(cnt, e2r, e2s, e2n, mark2, state, g1w, x1);
    k_dec<<<1, 896, 0, stream>>>(cnt, l1r, l1w, mark1, deg, x1, g2w, g2b,
                                 tpsf, past, dWih, dWhh, dbih, dbhh, fcw, fcb,
                                 (float*)d_out);
}

// Round 3
// 256.344 us; speedup vs baseline: 1.2197x; 1.2197x over previous
//
#include <hip/hip_runtime.h>
#include <math.h>

#define NN 65536
#define NE 1048576
#define KH 48
#define G3 144
#define DEGB 512

#define CAP_L1 8192
#define CAP_S1 4096
#define CAP_E2 65536
#define CAP_S2 8192

// ws byte offsets. First 524352 bytes (mark1|mark2|cnt) are zeroed by one
// hipMemsetAsync in kernel_launch.
#define OFF_MARK1  0u        // NN i32
#define OFF_MARK2  262144u   // NN i32
#define OFF_CNT    524288u   // 16 u32: [0]=cntL1 [1]=cntS1 [2]=cntE2 [3]=cntS2
#define OFF_L1R    524352u   // CAP_L1 i32
#define OFF_L1W    557120u   // CAP_L1 f32
#define OFF_S1G    589888u   // CAP_S1 i32 (S1 index -> global node id)
#define OFF_E2R    606272u   // CAP_E2 i32
#define OFF_E2S    868416u   // CAP_E2 i32
#define OFF_E2W    1130560u  // CAP_E2 f32 (raw weight; norm computed inline)
#define OFF_S2     1392704u  // CAP_S2 i32
#define OFF_DEG2   1425472u  // CAP_S2 f32 (compact degree, init 1.0)
#define OFF_STATE  1458240u  // CAP_S2*48 f32
#define OFF_X1     3031104u  // CAP_S1*48 f32
#define OFF_TPSF   3817536u  // 128 f32: [0..47]=target_past, [64..111]=state_fut

typedef _Float16 h2_t __attribute__((ext_vector_type(2)));

__device__ __forceinline__ float sigmf(float x) { return 1.0f / (1.0f + expf(-x)); }

#if __has_builtin(__builtin_amdgcn_fdot2)
__device__ __forceinline__ float fdot2f(h2_t a, h2_t b, float c) {
    return __builtin_amdgcn_fdot2(a, b, c, false);
}
#else
__device__ __forceinline__ float fdot2f(h2_t a, h2_t b, float c) {
    return c + (float)a.x * (float)b.x + (float)a.y * (float)b.y;
}
#endif

// ---------------- K1: find edges into node 0 (4 edges/thread) --------------
__global__ void k_edges1(const int* ei, const float* ew,
                         int* mark1, unsigned* cnt, int* l1r, float* l1w) {
    int q = blockIdx.x * blockDim.x + threadIdx.x;
    if (q >= NE / 4) return;
    if (q == 0) mark1[0] = 1;   // node 0 always in S1
    int4 c4 = reinterpret_cast<const int4*>(ei + NE)[q];
    int e = q * 4;
    int cc[4] = {c4.x, c4.y, c4.z, c4.w};
#pragma unroll
    for (int j = 0; j < 4; ++j) {
        if (cc[j] == 0) {
            int r = ei[e + j];
            float w = ew[e + j];
            unsigned s = atomicAdd(&cnt[0], 1u);
            if (s < CAP_L1) { l1r[s] = r; l1w[s] = w; }
            mark1[r] = 1;
        }
    }
}

// ---------------- K2: compact S1; emit self-loop E2 entries; init x1 -------
__global__ void k_compact1(int* mark1, int* mark2, unsigned* cnt,
                           int* e2r, int* e2s, float* e2w, int* s1g,
                           float* x1, const float* g1b) {
    int i = blockIdx.x * blockDim.x + threadIdx.x;
    if (i >= NN) return;
    if (mark1[i]) {
        unsigned s = atomicAdd(&cnt[1], 1u);
        if (s < CAP_S1) {
            mark1[i] = (int)s + 1;
            mark2[i] = 1;               // needs GRU state (self loop row)
            s1g[s] = i;
            unsigned t = atomicAdd(&cnt[2], 1u);
            if (t < CAP_E2) { e2r[t] = i; e2s[t] = (int)s; e2w[t] = 1.0f; }
            for (int k = 0; k < KH; ++k) x1[s * KH + k] = g1b[k];
        } else {
            mark1[i] = 0;
        }
    }
}

// ---------------- K3: collect edges into S1 (4 edges/thread) ---------------
__global__ void k_edges2(const int* ei, const float* ew,
                         const int* mark1, int* mark2, unsigned* cnt,
                         int* e2r, int* e2s, float* e2w) {
    int q = blockIdx.x * blockDim.x + threadIdx.x;
    if (q >= NE / 4) return;
    int4 c4 = reinterpret_cast<const int4*>(ei + NE)[q];
    int e = q * 4;
    int cc[4] = {c4.x, c4.y, c4.z, c4.w};
#pragma unroll
    for (int j = 0; j < 4; ++j) {
        int m = mark1[cc[j]];
        if (m > 0) {
            int r = ei[e + j];
            float w = ew[e + j];
            unsigned s = atomicAdd(&cnt[2], 1u);
            if (s < CAP_E2) { e2r[s] = r; e2s[s] = m - 1; e2w[s] = w; }
            mark2[r] = 1;
        }
    }
}

// ---------------- K4: compact S2; init compact degree ----------------------
__global__ void k_compact2(int* mark2, unsigned* cnt, int* s2, float* deg2) {
    int i = blockIdx.x * blockDim.x + threadIdx.x;
    if (i >= NN) return;
    if (mark2[i]) {
        unsigned s = atomicAdd(&cnt[3], 1u);
        if (s < CAP_S2) { s2[s] = i; mark2[i] = (int)s + 1; deg2[s] = 1.0f; }
        else mark2[i] = 0;
    }
}

// ---------------- conv1d(pad=1,k=3) + GRU over one sequence ----------------
__device__ void gru_seq(const float* xseq, int T,
                        const float* cw, const float* cb,
                        const float* Wih, const float* Whh,
                        const float* bih, const float* bhh,
                        float* out48,
                        float* s_x, float* s_embed, float* s_giA,
                        float* s_h, float* s_gh) {
    int t = threadIdx.x;
    int nt = blockDim.x;
    for (int i = t; i < T * 2; i += nt) s_x[i] = xseq[i];
    __syncthreads();
    for (int idx = t; idx < T * KH; idx += nt) {
        int tt = idx / KH;
        int k = idx - tt * KH;
        float acc = cb[k];
#pragma unroll
        for (int d = 0; d < 3; ++d) {
            int tau = tt + d - 1;
            if (tau >= 0 && tau < T) {
                acc += cw[k * 6 + d] * s_x[tau * 2 + 0];
                acc += cw[k * 6 + 3 + d] * s_x[tau * 2 + 1];
            }
        }
        s_embed[tt * KH + k] = fmaxf(acc, 0.0f);
    }
    __syncthreads();
    // gi = Wih@embed + bih for all steps (parallel; not recurrent)
    for (int idx = t; idx < T * G3; idx += nt) {
        int step = idx / G3;
        int row = idx - step * G3;
        const float4* wp = reinterpret_cast<const float4*>(Wih + row * KH);
        const float4* em = reinterpret_cast<const float4*>(s_embed + step * KH);
        float g = bih[row];
#pragma unroll
        for (int j = 0; j < 12; ++j) {
            float4 w4 = wp[j]; float4 e4 = em[j];
            g += w4.x * e4.x + w4.y * e4.y + w4.z * e4.z + w4.w * e4.w;
        }
        s_giA[idx] = g;
    }
    float4 wh[12];
    float bh = 0.0f;
    if (t < G3) {
        const float4* q = reinterpret_cast<const float4*>(Whh + t * KH);
#pragma unroll
        for (int j = 0; j < 12; ++j) wh[j] = q[j];
        bh = bhh[t];
    }
    if (t < KH) s_h[t] = 0.0f;
    __syncthreads();
    for (int step = 0; step < T; ++step) {
        if (t < G3) {
            const float4* hp = reinterpret_cast<const float4*>(s_h);
            float g = bh;
#pragma unroll
            for (int j = 0; j < 12; ++j) {
                float4 h4 = hp[j];
                g += wh[j].x * h4.x + wh[j].y * h4.y + wh[j].z * h4.z + wh[j].w * h4.w;
            }
            s_gh[t] = g;
        }
        __syncthreads();
        if (t < KH) {
            const float* gi = s_giA + step * G3;
            float r = sigmf(gi[t] + s_gh[t]);
            float z = sigmf(gi[KH + t] + s_gh[KH + t]);
            float n = tanhf(gi[2 * KH + t] + r * s_gh[2 * KH + t]);
            s_h[t] = (1.0f - z) * n + z * s_h[t];
        }
        __syncthreads();
    }
    if (t < KH) out48[t] = s_h[t];
}

// ---------------- K5: deg scan + all GRUs (fused; independent outputs) -----
__global__ __launch_bounds__(192, 2) void k_gru(
    const float* x, const float* cpw, const float* cpb,
    const float* epWih, const float* epWhh, const float* epbih, const float* epbhh,
    const float* cfw, const float* cfb,
    const float* efWih, const float* efWhh, const float* efbih, const float* efbhh,
    const float* past, const float* future,
    const int* ei, const float* ew, const int* mark2, float* deg2,
    const int* s2, const unsigned* cnt, float* state, float* tpsf) {
    if (blockIdx.x < DEGB) {
        // degree accumulation for S2 nodes only (~5K atomics total)
        int per = NE / DEGB;
        int lo = blockIdx.x * per;
        for (int e = lo + threadIdx.x; e < lo + per; e += blockDim.x) {
            int c = ei[NE + e];
            int m = mark2[c];
            if (m > 0) atomicAdd(&deg2[m - 1], ew[e]);
        }
        return;
    }
    __shared__ __align__(16) float s_x[80];
    __shared__ __align__(16) float s_embed[40 * KH];
    __shared__ __align__(16) float s_giA[40 * G3];
    __shared__ __align__(16) float s_h[KH];
    __shared__ float s_gh[G3];
    if (blockIdx.x == DEGB) {
        gru_seq(past, 20, cpw, cpb, epWih, epWhh, epbih, epbhh,
                tpsf, s_x, s_embed, s_giA, s_h, s_gh);
        return;
    }
    if (blockIdx.x == DEGB + 1) {
        gru_seq(future, 40, cfw, cfb, efWih, efWhh, efbih, efbhh,
                tpsf + 64, s_x, s_embed, s_giA, s_h, s_gh);
        return;
    }
    int b0 = blockIdx.x - (DEGB + 2);
    int nw = gridDim.x - (DEGB + 2);
    int cnt2 = (int)min(cnt[3], (unsigned)CAP_S2);
    for (int b = b0; b < cnt2; b += nw) {
        int node = s2[b];
        gru_seq(x + (size_t)node * 40, 20, cpw, cpb, epWih, epWhh, epbih, epbhh,
                state + (size_t)b * KH, s_x, s_embed, s_giA, s_h, s_gh);
    }
}

// ---------------- K6: GCN layer 1 edge accumulation (norm inline) ----------
__global__ void k_acc1(const unsigned* cnt, const int* e2r, const int* e2s,
                       const float* e2w, const int* mark2, const float* deg2,
                       const int* s1g, const float* state,
                       const float* W1, float* x1) {
    int nE = (int)min(cnt[2], (unsigned)CAP_E2);
    int total = nE * KH;
    int stride = gridDim.x * blockDim.x;
    for (int idx = blockIdx.x * blockDim.x + threadIdx.x; idx < total; idx += stride) {
        int e = idx / KH;
        int k = idx - e * KH;
        int row = e2r[e];
        int s2i = mark2[row] - 1;
        if (s2i < 0) continue;
        int cglob = s1g[e2s[e]];
        int cs2 = mark2[cglob] - 1;
        float norm = e2w[e] * rsqrtf(deg2[s2i] * deg2[cs2]);
        const float* sp = state + (size_t)s2i * KH;
        const float* wp = W1 + k * KH;
        float acc = 0.0f;
#pragma unroll
        for (int m = 0; m < KH; ++m) acc += sp[m] * wp[m];
        atomicAdd(&x1[e2s[e] * KH + k], acc * norm);
    }
}

// ---------------- K7: GCN layer 2 @ node 0 + decoder -----------------------
// dWhh half-row per thread as f16 half2 (36 VGPRs) + f32 accumulate via
// v_dot2_f32_f16; __launch_bounds__(896,4) -> 128-VGPR budget, no spill.
__global__ __launch_bounds__(896, 4) void k_dec(
    const unsigned* cnt, const int* l1r, const float* l1w,
    const int* mark1, const int* mark2, const float* deg2, const float* x1,
    const float* W2, const float* b2, const float* tpsf, const float* past,
    const float* dWih, const float* dWhh, const float* dbih, const float* dbhh,
    const float* fcw, const float* fcb, float* out) {
    __shared__ __align__(16) float s_conc[G3];
    __shared__ __align__(16) float s_h[G3];
    __shared__ __align__(8) _Float16 s_h16[G3];
    __shared__ float s_gi0[3 * G3], s_gh[3 * G3], s_bih[3 * G3];
    int t = threadIdx.x;
    if (t < 48) s_conc[t] = b2[t];
    else if (t < 96) s_conc[t] = tpsf[t - 48];
    else if (t < 144) s_conc[t] = tpsf[64 + t - 96];
    if (t < 3 * G3) s_bih[t] = dbih[t];
    if (t < G3) { s_h[t] = 0.0f; s_h16[t] = (_Float16)0.0f; }
    __syncthreads();
    // layer-2 message accumulation into s_conc[0..47]
    int cl1 = (int)min(cnt[0], (unsigned)CAP_L1);
    float dinv0 = rsqrtf(deg2[mark2[0] - 1]);
    int items = (cl1 + 1) * KH;
    for (int idx = t; idx < items; idx += blockDim.x) {
        int e = idx / KH;
        int k = idx - e * KH;
        int row; float norm;
        if (e == cl1) { row = 0; norm = dinv0 * dinv0; }
        else {
            row = l1r[e];
            int rs2 = mark2[row] - 1;
            if (rs2 < 0) continue;
            norm = l1w[e] * rsqrtf(deg2[rs2]) * dinv0;
        }
        int s1 = mark1[row] - 1;
        if (s1 < 0) continue;
        const float* xp = x1 + (size_t)s1 * KH;
        const float* wp = W2 + k * KH;
        float acc = 0.0f;
#pragma unroll
        for (int m = 0; m < KH; ++m) acc += fmaxf(xp[m], 0.0f) * wp[m];
        atomicAdd(&s_conc[k], acc * norm);
    }
    // decoder: half-row of dWhh per thread, f16
    int row = t >> 1, hf = t & 1;
    h2_t wh[36];
    float bh2 = 0.0f;
    if (t < 864) {
        const float4* q = reinterpret_cast<const float4*>(dWhh + row * G3 + hf * 72);
#pragma unroll
        for (int jj = 0; jj < 18; ++jj) {
            float4 f = q[jj];
            h2_t a, b;
            a.x = (_Float16)f.x; a.y = (_Float16)f.y;
            b.x = (_Float16)f.z; b.y = (_Float16)f.w;
            wh[2 * jj] = a; wh[2 * jj + 1] = b;
        }
        if (hf == 0) bh2 = dbhh[row];
    }
    float pres = 0.0f;
    if (t == 0 || t == 64) pres = past[38 + (t >> 6)];
    __syncthreads();   // s_conc complete, s_h16 ready
    // gi at step 0 (steps >=1: input zeros -> gi = bih)
    if (t < 864) {
        const float4* p = reinterpret_cast<const float4*>(dWih + row * G3 + hf * 72);
        const float4* cc = reinterpret_cast<const float4*>(s_conc + hf * 72);
        float g = 0.0f;
#pragma unroll
        for (int j = 0; j < 18; ++j) {
            float4 w4 = p[j]; float4 c4 = cc[j];
            g += w4.x * c4.x + w4.y * c4.y + w4.z * c4.z + w4.w * c4.w;
        }
        g += __shfl_xor(g, 1);
        if (hf == 0) s_gi0[row] = g + s_bih[row];
    }
    for (int i = 0; i < 40; ++i) {
        if (t < 864) {
            const h2_t* hp = reinterpret_cast<const h2_t*>(s_h16 + hf * 72);
            float g = 0.0f;
#pragma unroll
            for (int j = 0; j < 36; ++j) g = fdot2f(wh[j], hp[j], g);
            g += __shfl_xor(g, 1);
            if (hf == 0) s_gh[row] = g + bh2;
        }
        __syncthreads();
        if (t < G3) {
            float gr = (i == 0) ? s_gi0[t] : s_bih[t];
            float gz = (i == 0) ? s_gi0[G3 + t] : s_bih[G3 + t];
            float gn = (i == 0) ? s_gi0[2 * G3 + t] : s_bih[2 * G3 + t];
            float r = sigmf(gr + s_gh[t]);
            float z = sigmf(gz + s_gh[G3 + t]);
            float n = tanhf(gn + r * s_gh[2 * G3 + t]);
            float hnew = (1.0f - z) * n + z * s_h[t];
            s_h[t] = hnew;
            s_h16[t] = (_Float16)hnew;
        }
        __syncthreads();
        int w = t >> 6;
        if (w < 2) {
            int lane = t & 63;
            float p = 0.0f;
            for (int m = lane; m < G3; m += 64) p += s_h[m] * fcw[w * G3 + m];
#pragma unroll
            for (int off = 32; off > 0; off >>= 1) p += __shfl_down(p, off);
            if (lane == 0) {
                pres += p + fcb[w];
                out[i * 2 + w] = pres;
            }
        }
    }
}

extern "C" void kernel_launch(void* const* d_in, const int* in_sizes, int n_in,
                              void* d_out, int out_size, void* d_ws, size_t ws_size,
                              hipStream_t stream) {
    (void)in_sizes; (void)n_in; (void)out_size; (void)ws_size;
    const float* past   = (const float*)d_in[0];
    const float* future = (const float*)d_in[1];
    const float* x      = (const float*)d_in[2];
    const int*   ei     = (const int*)d_in[3];
    const float* ew     = (const float*)d_in[4];
    const float* cpw    = (const float*)d_in[5];
    const float* cpb    = (const float*)d_in[6];
    const float* cfw    = (const float*)d_in[7];
    const float* cfb    = (const float*)d_in[8];
    const float* epWih  = (const float*)d_in[9];
    const float* epWhh  = (const float*)d_in[10];
    const float* epbih  = (const float*)d_in[11];
    const float* epbhh  = (const float*)d_in[12];
    const float* efWih  = (const float*)d_in[13];
    const float* efWhh  = (const float*)d_in[14];
    const float* efbih  = (const float*)d_in[15];
    const float* efbhh  = (const float*)d_in[16];
    const float* dWih   = (const float*)d_in[17];
    const float* dWhh   = (const float*)d_in[18];
    const float* dbih   = (const float*)d_in[19];
    const float* dbhh   = (const float*)d_in[20];
    const float* fcw    = (const float*)d_in[21];
    const float* fcb    = (const float*)d_in[22];
    const float* g1w    = (const float*)d_in[23];
    const float* g1b    = (const float*)d_in[24];
    const float* g2w    = (const float*)d_in[25];
    const float* g2b    = (const float*)d_in[26];

    char* ws = (char*)d_ws;
    int*      mark1 = (int*)(ws + OFF_MARK1);
    int*      mark2 = (int*)(ws + OFF_MARK2);
    unsigned* cnt   = (unsigned*)(ws + OFF_CNT);
    int*      l1r   = (int*)(ws + OFF_L1R);
    float*    l1w   = (float*)(ws + OFF_L1W);
    int*      s1g   = (int*)(ws + OFF_S1G);
    int*      e2r   = (int*)(ws + OFF_E2R);
    int*      e2s   = (int*)(ws + OFF_E2S);
    float*    e2w   = (float*)(ws + OFF_E2W);
    int*      s2    = (int*)(ws + OFF_S2);
    float*    deg2  = (float*)(ws + OFF_DEG2);
    float*    state = (float*)(ws + OFF_STATE);
    float*    x1    = (float*)(ws + OFF_X1);
    float*    tpsf  = (float*)(ws + OFF_TPSF);

    hipMemsetAsync(ws, 0, 524352, stream);  // mark1 | mark2 | cnt
    k_edges1<<<NE / 4 / 256, 256, 0, stream>>>(ei, ew, mark1, cnt, l1r, l1w);
    k_compact1<<<NN / 256, 256, 0, stream>>>(mark1, mark2, cnt, e2r, e2s, e2w, s1g, x1, g1b);
    k_edges2<<<NE / 4 / 256, 256, 0, stream>>>(ei, ew, mark1, mark2, cnt, e2r, e2s, e2w);
    k_compact2<<<NN / 256, 256, 0, stream>>>(mark2, cnt, s2, deg2);
    k_gru<<<DEGB + 2 + 512, 192, 0, stream>>>(x, cpw, cpb, epWih, epWhh, epbih, epbhh,
                                              cfw, cfb, efWih, efWhh, efbih, efbhh,
                                              past, future, ei, ew, mark2, deg2,
                                              s2, cnt, state, tpsf);
    k_acc1<<<128, 256, 0, stream>>>(cnt, e2r, e2s, e2w, mark2, deg2, s1g, state, g1w, x1);
    k_dec<<<1, 896, 0, stream>>>(cnt, l1r, l1w, mark1, mark2, deg2, x1, g2w, g2b,
                                 tpsf, past, dWih, dWhh, dbih, dbhh, fcw, fcb,
                                 (float*)d_out);
}